// Round 3
// baseline (379.752 us; speedup 1.0000x reference)
//
#include <hip/hip_runtime.h>

#define SDIM 2048
#define EDIM 768
#define HDIM 12
#define DDIM 64
#define BDIM 4
#define MROWS (BDIM * SDIM)   // 8192
#define NQKV (3 * EDIM)       // 2304
#define NBH (BDIM * HDIM)     // 48

typedef __attribute__((ext_vector_type(8))) short s16x8;   // 8 bf16
typedef __attribute__((ext_vector_type(4))) float f32x4;

__device__ __forceinline__ short f2b(float x) {
  union { float f; unsigned u; } v; v.f = x;
  unsigned r = v.u + 0x7fffu + ((v.u >> 16) & 1u);
  return (short)(r >> 16);
}

// ---------------- elementwise fp32 -> bf16 ----------------
__global__ __launch_bounds__(256) void convert_bf16(
    const float* __restrict__ in, short* __restrict__ out, int n4) {
  int i = blockIdx.x * 256 + threadIdx.x;
  int stride = gridDim.x * 256;
  for (; i < n4; i += stride) {
    float4 v = ((const float4*)in)[i];
    short4 o;
    o.x = f2b(v.x); o.y = f2b(v.y); o.z = f2b(v.z); o.w = f2b(v.w);
    ((short4*)out)[i] = o;
  }
}

// ---------------- transpose + convert: [K][N] f32 -> [N][K] bf16 ----------------
__global__ __launch_bounds__(256) void transpose_bf16(
    const float* __restrict__ in, short* __restrict__ out, int K, int N) {
  __shared__ float t[32][33];
  int n0 = blockIdx.x * 32, k0 = blockIdx.y * 32;
  int tx = threadIdx.x & 31, ty = threadIdx.x >> 5;  // ty 0..7
#pragma unroll
  for (int i = 0; i < 4; ++i)
    t[ty + 8 * i][tx] = in[(size_t)(k0 + ty + 8 * i) * N + n0 + tx];
  __syncthreads();
#pragma unroll
  for (int i = 0; i < 4; ++i)
    out[(size_t)(n0 + ty + 8 * i) * K + k0 + tx] = f2b(t[tx][ty + 8 * i]);
}

// ---------------- bf16 MFMA GEMM, 128x128 tile, BK=32, 4 waves ----------------
__global__ __launch_bounds__(256) void gemm_bf16(
    const short* __restrict__ A, const short* __restrict__ Bt,
    const float* __restrict__ bias, int M, int N, int K, int mode,
    short* __restrict__ qout, short* __restrict__ kout,
    short* __restrict__ vout, float* __restrict__ fout) {
  __shared__ short As[128 * 32];
  __shared__ short Bs[128 * 32];
  const int tid = threadIdx.x;
  const int l = tid & 63, w = tid >> 6;
  const int lr = l & 15, g = l >> 4;
  const int bm = blockIdx.y * 128, bn = blockIdx.x * 128;
  const int wm = w >> 1, wn = w & 1;

  f32x4 acc[4][4];
  const f32x4 z4 = {0.f, 0.f, 0.f, 0.f};
#pragma unroll
  for (int m = 0; m < 4; ++m)
#pragma unroll
    for (int n = 0; n < 4; ++n) acc[m][n] = z4;

  for (int k0 = 0; k0 < K; k0 += 32) {
    __syncthreads();
#pragma unroll
    for (int it = 0; it < 2; ++it) {
      int row = w * 16 + lr + 64 * it;
      s16x8 va = *(const s16x8*)(A + (size_t)(bm + row) * K + k0 + g * 8);
      s16x8 vb = *(const s16x8*)(Bt + (size_t)(bn + row) * K + k0 + g * 8);
      int byte = (row * 64 + g * 16) ^ ((((unsigned)row >> 1) & 7) << 4);
      *(s16x8*)((char*)As + byte) = va;
      *(s16x8*)((char*)Bs + byte) = vb;
    }
    __syncthreads();
    s16x8 af[4], bfr[4];
#pragma unroll
    for (int m = 0; m < 4; ++m) {
      int row = wm * 64 + m * 16 + lr;
      int byte = (row * 64 + g * 16) ^ ((((unsigned)row >> 1) & 7) << 4);
      af[m] = *(const s16x8*)((char*)As + byte);
    }
#pragma unroll
    for (int n = 0; n < 4; ++n) {
      int row = wn * 64 + n * 16 + lr;
      int byte = (row * 64 + g * 16) ^ ((((unsigned)row >> 1) & 7) << 4);
      bfr[n] = *(const s16x8*)((char*)Bs + byte);
    }
#pragma unroll
    for (int m = 0; m < 4; ++m)
#pragma unroll
      for (int n = 0; n < 4; ++n)
        acc[m][n] = __builtin_amdgcn_mfma_f32_16x16x32_bf16(af[m], bfr[n],
                                                            acc[m][n], 0, 0, 0);
  }

#pragma unroll
  for (int m = 0; m < 4; ++m) {
    int rbase = bm + wm * 64 + m * 16 + g * 4;
#pragma unroll
    for (int n = 0; n < 4; ++n) {
      int col = bn + wn * 64 + n * 16 + lr;
      float bv = bias[col];
      if (mode == 0) {
        int which = (col >= 1536) ? 2 : (col >= 768 ? 1 : 0);
        int rem = col - which * 768;
        int h = rem >> 6, d = rem & 63;
#pragma unroll
        for (int i = 0; i < 4; ++i) {
          int r = rbase + i;
          int b = r >> 11, s = r & 2047;
          short o = f2b(acc[m][n][i] + bv);
          size_t bh = (size_t)b * HDIM + h;
          if (which == 0)      qout[(bh * SDIM + s) * DDIM + d] = o;
          else if (which == 1) kout[(bh * SDIM + s) * DDIM + d] = o;
          else                 vout[(bh * DDIM + d) * SDIM + s] = o;  // V transposed
        }
      } else {
#pragma unroll
        for (int i = 0; i < 4; ++i)
          fout[(size_t)(rbase + i) * N + col] = acc[m][n][i] + bv;
      }
    }
  }
}

// ---------------- flash attention v2: barrier-free, K/V frags from global ----
// qb,kb: [BH][S][D] bf16 ; vb: [BH][D][S] bf16 ; ao: [B*S][E] bf16
// Block = 4 independent waves; wave owns 32 q-rows (2 m-frags). No __syncthreads.
__global__ __launch_bounds__(256) void attn_mfma2(
    const short* __restrict__ qb, const short* __restrict__ kb,
    const short* __restrict__ vb, short* __restrict__ ao) {
  __shared__ float Ss[4][2][16 * 64];  // per-wave, per-m P strips (swizzled)
  const int tid = threadIdx.x;
  const int l = tid & 63, w = tid >> 6;
  const int lr = l & 15, g = l >> 4;
  const int qt = gridDim.x - 1 - blockIdx.x;  // long blocks first
  const int bh = blockIdx.y;
  const size_t base = (size_t)bh * SDIM * DDIM;
  const int q0 = qt * 128 + w * 32;
  const float SC = 0.125f * 1.4426950408889634f;  // scale * log2(e)

  // Q A-fragments in registers: 2 m-frags x 2 k-steps
  s16x8 qa[2][2];
#pragma unroll
  for (int m = 0; m < 2; ++m)
#pragma unroll
    for (int s = 0; s < 2; ++s)
      qa[m][s] = *(const s16x8*)(qb + base +
                                 (size_t)(q0 + m * 16 + lr) * DDIM + s * 32 + g * 8);

  const f32x4 z4 = {0.f, 0.f, 0.f, 0.f};
  f32x4 acco[2][4];
#pragma unroll
  for (int m = 0; m < 2; ++m)
#pragma unroll
    for (int nd = 0; nd < 4; ++nd) acco[m][nd] = z4;
  float mrun[2][4], lrun[2][4];
#pragma unroll
  for (int m = 0; m < 2; ++m)
#pragma unroll
    for (int i = 0; i < 4; ++i) { mrun[m][i] = -1e30f; lrun[m][i] = 0.f; }

  const int nkt = (q0 >> 6) + 1;
  for (int kt = 0; kt < nkt; ++kt) {
    // K B-fragments direct from global (L1-resident after first wave)
    s16x8 kf[4][2];
#pragma unroll
    for (int nt = 0; nt < 4; ++nt)
#pragma unroll
      for (int s = 0; s < 2; ++s)
        kf[nt][s] = *(const s16x8*)(kb + base +
            (size_t)(kt * 64 + nt * 16 + lr) * DDIM + s * 32 + g * 8);

    // S = Q K^T
    f32x4 sacc[2][4];
#pragma unroll
    for (int m = 0; m < 2; ++m)
#pragma unroll
      for (int nt = 0; nt < 4; ++nt) sacc[m][nt] = z4;
#pragma unroll
    for (int s = 0; s < 2; ++s)
#pragma unroll
      for (int m = 0; m < 2; ++m)
#pragma unroll
        for (int nt = 0; nt < 4; ++nt)
          sacc[m][nt] = __builtin_amdgcn_mfma_f32_16x16x32_bf16(
              qa[m][s], kf[nt][s], sacc[m][nt], 0, 0, 0);

    // V B-fragments: issue now, consumed after softmax (latency hidden)
    s16x8 vf[4][2];
#pragma unroll
    for (int nd = 0; nd < 4; ++nd)
#pragma unroll
      for (int s = 0; s < 2; ++s)
        vf[nd][s] = *(const s16x8*)(vb + base +
            (size_t)(nd * 16 + lr) * SDIM + kt * 64 + s * 32 + g * 8);

    // scale (+ mask only on the diagonal tile) + row max
    float pmax[2][4];
#pragma unroll
    for (int m = 0; m < 2; ++m)
#pragma unroll
      for (int i = 0; i < 4; ++i) pmax[m][i] = -1e30f;
    if (kt == nkt - 1) {
#pragma unroll
      for (int m = 0; m < 2; ++m)
#pragma unroll
        for (int nt = 0; nt < 4; ++nt)
#pragma unroll
          for (int i = 0; i < 4; ++i) {
            float sv = sacc[m][nt][i] * SC;
            int qrow = q0 + m * 16 + g * 4 + i;
            int kcol = kt * 64 + nt * 16 + lr;
            sv = (kcol > qrow) ? -1e30f : sv;
            sacc[m][nt][i] = sv;
            pmax[m][i] = fmaxf(pmax[m][i], sv);
          }
    } else {
#pragma unroll
      for (int m = 0; m < 2; ++m)
#pragma unroll
        for (int nt = 0; nt < 4; ++nt)
#pragma unroll
          for (int i = 0; i < 4; ++i) {
            float sv = sacc[m][nt][i] * SC;
            sacc[m][nt][i] = sv;
            pmax[m][i] = fmaxf(pmax[m][i], sv);
          }
    }
#pragma unroll
    for (int off = 1; off < 16; off <<= 1)
#pragma unroll
      for (int m = 0; m < 2; ++m)
#pragma unroll
        for (int i = 0; i < 4; ++i)
          pmax[m][i] = fmaxf(pmax[m][i], __shfl_xor(pmax[m][i], off, 64));

    // defer-rescale (T13): only rescale when max grew past threshold
    bool need = false;
#pragma unroll
    for (int m = 0; m < 2; ++m)
#pragma unroll
      for (int i = 0; i < 4; ++i)
        need = need || (pmax[m][i] > mrun[m][i] + 8.0f);
    if (__any(need)) {
#pragma unroll
      for (int m = 0; m < 2; ++m)
#pragma unroll
        for (int i = 0; i < 4; ++i) {
          float nm = fmaxf(mrun[m][i], pmax[m][i]);
          float al = exp2f(mrun[m][i] - nm);
          lrun[m][i] *= al;
#pragma unroll
          for (int nd = 0; nd < 4; ++nd) acco[m][nd][i] *= al;
          mrun[m][i] = nm;
        }
    }

    // P = exp2(S - m): per-lane l partials, swizzled strip write
#pragma unroll
    for (int m = 0; m < 2; ++m) {
      char* ssb = (char*)Ss[w][m];
#pragma unroll
      for (int nt = 0; nt < 4; ++nt)
#pragma unroll
        for (int i = 0; i < 4; ++i) {
          float p = exp2f(sacc[m][nt][i] - mrun[m][i]);
          lrun[m][i] += p;
          int row = g * 4 + i;
          int wbyte = (row * 256 + (nt * 16 + lr) * 4) ^ ((row & 7) << 4);
          *(float*)(ssb + wbyte) = p;
        }
    }

    // PV
#pragma unroll
    for (int m = 0; m < 2; ++m) {
      char* ssb = (char*)Ss[w][m];
#pragma unroll
      for (int s = 0; s < 2; ++s) {
        int pbyte = (lr * 256 + s * 128 + g * 32) ^ ((lr & 7) << 4);
        f32x4 p0 = *(const f32x4*)(ssb + pbyte);
        f32x4 p1 = *(const f32x4*)(ssb + (pbyte ^ 16));
        s16x8 pa;
#pragma unroll
        for (int j = 0; j < 4; ++j) pa[j] = f2b(p0[j]);
#pragma unroll
        for (int j = 0; j < 4; ++j) pa[4 + j] = f2b(p1[j]);
#pragma unroll
        for (int nd = 0; nd < 4; ++nd)
          acco[m][nd] = __builtin_amdgcn_mfma_f32_16x16x32_bf16(
              pa, vf[nd][s], acco[m][nd], 0, 0, 0);
      }
    }
  }

  // final l reduction (moved out of the kt loop)
#pragma unroll
  for (int off = 1; off < 16; off <<= 1)
#pragma unroll
    for (int m = 0; m < 2; ++m)
#pragma unroll
      for (int i = 0; i < 4; ++i)
        lrun[m][i] += __shfl_xor(lrun[m][i], off, 64);

  const int b = bh / HDIM, h = bh % HDIM;
#pragma unroll
  for (int m = 0; m < 2; ++m)
#pragma unroll
    for (int i = 0; i < 4; ++i) {
      float inv = 1.0f / lrun[m][i];
      int r = q0 + m * 16 + g * 4 + i;
      size_t orow = ((size_t)b * SDIM + r) * EDIM + h * DDIM;
#pragma unroll
      for (int nd = 0; nd < 4; ++nd)
        ao[orow + nd * 16 + lr] = f2b(acco[m][nd][i] * inv);
    }
}

extern "C" void kernel_launch(void* const* d_in, const int* in_sizes, int n_in,
                              void* d_out, int out_size, void* d_ws,
                              size_t ws_size, hipStream_t stream) {
  const float* x = (const float*)d_in[0];
  const float* w_qkv = (const float*)d_in[1];
  const float* b_qkv = (const float*)d_in[2];
  const float* w_proj = (const float*)d_in[3];
  const float* b_proj = (const float*)d_in[4];
  float* out = (float*)d_out;

  char* p = (char*)d_ws;
  short* xb = (short*)p;      p += (size_t)MROWS * EDIM * 2;
  short* wqkvt = (short*)p;   p += (size_t)NQKV * EDIM * 2;
  short* wprojt = (short*)p;  p += (size_t)EDIM * EDIM * 2;
  short* qbuf = (short*)p;    p += (size_t)NBH * SDIM * DDIM * 2;
  short* kbuf = (short*)p;    p += (size_t)NBH * SDIM * DDIM * 2;
  short* vbuf = (short*)p;    p += (size_t)NBH * SDIM * DDIM * 2;
  short* aob = (short*)p;     p += (size_t)MROWS * EDIM * 2;

  dim3 blk(256);
  convert_bf16<<<dim3(2048), blk, 0, stream>>>(x, xb, MROWS * EDIM / 4);
  transpose_bf16<<<dim3(NQKV / 32, EDIM / 32), blk, 0, stream>>>(w_qkv, wqkvt, EDIM, NQKV);
  transpose_bf16<<<dim3(EDIM / 32, EDIM / 32), blk, 0, stream>>>(w_proj, wprojt, EDIM, EDIM);
  gemm_bf16<<<dim3(NQKV / 128, MROWS / 128), blk, 0, stream>>>(
      xb, wqkvt, b_qkv, MROWS, NQKV, EDIM, 0, qbuf, kbuf, vbuf, nullptr);
  attn_mfma2<<<dim3(SDIM / 128, NBH), blk, 0, stream>>>(qbuf, kbuf, vbuf, aob);
  gemm_bf16<<<dim3(EDIM / 128, MROWS / 128), blk, 0, stream>>>(
      aob, wprojt, b_proj, MROWS, EDIM, EDIM, 1, nullptr, nullptr, nullptr, out);
}

// Round 4
// 199.580 us; speedup vs baseline: 1.9028x; 1.9028x over previous
//
#include <hip/hip_runtime.h>

#define SDIM 2048
#define EDIM 768
#define HDIM 12
#define DDIM 64
#define BDIM 4
#define MROWS (BDIM * SDIM)   // 8192
#define NQKV (3 * EDIM)       // 2304
#define NBH (BDIM * HDIM)     // 48
#define NTILE 32              // 2048 / 64 q-tiles
#define NPAIR 16

typedef __attribute__((ext_vector_type(8))) short s16x8;   // 8 bf16
typedef __attribute__((ext_vector_type(4))) float f32x4;
typedef __attribute__((ext_vector_type(2))) unsigned int u32x2;

__device__ __forceinline__ short f2b(float x) {
  union { float f; unsigned u; } v; v.f = x;
  unsigned r = v.u + 0x7fffu + ((v.u >> 16) & 1u);
  return (short)(r >> 16);
}

__device__ __forceinline__ unsigned cvtpk(float lo, float hi) {
  unsigned r;
  asm volatile("v_cvt_pk_bf16_f32 %0, %1, %2" : "=v"(r) : "v"(lo), "v"(hi));
  return r;
}

__device__ __forceinline__ void gld16(const void* g, void* l) {
  __builtin_amdgcn_global_load_lds(
      (const __attribute__((address_space(1))) unsigned int*)g,
      (__attribute__((address_space(3))) unsigned int*)l, 16, 0, 0);
}

// ---------------- elementwise fp32 -> bf16 ----------------
__global__ __launch_bounds__(256) void convert_bf16(
    const float* __restrict__ in, short* __restrict__ out, int n4) {
  int i = blockIdx.x * 256 + threadIdx.x;
  int stride = gridDim.x * 256;
  for (; i < n4; i += stride) {
    float4 v = ((const float4*)in)[i];
    short4 o;
    o.x = f2b(v.x); o.y = f2b(v.y); o.z = f2b(v.z); o.w = f2b(v.w);
    ((short4*)out)[i] = o;
  }
}

// ---------------- transpose + convert: [K][N] f32 -> [N][K] bf16 ----------------
__global__ __launch_bounds__(256) void transpose_bf16(
    const float* __restrict__ in, short* __restrict__ out, int K, int N) {
  __shared__ float t[32][33];
  int n0 = blockIdx.x * 32, k0 = blockIdx.y * 32;
  int tx = threadIdx.x & 31, ty = threadIdx.x >> 5;  // ty 0..7
#pragma unroll
  for (int i = 0; i < 4; ++i)
    t[ty + 8 * i][tx] = in[(size_t)(k0 + ty + 8 * i) * N + n0 + tx];
  __syncthreads();
#pragma unroll
  for (int i = 0; i < 4; ++i)
    out[(size_t)(n0 + ty + 8 * i) * K + k0 + tx] = f2b(t[tx][ty + 8 * i]);
}

// ---------------- bf16 MFMA GEMM, 128x128 tile, BK=32, 4 waves ----------------
__global__ __launch_bounds__(256) void gemm_bf16(
    const short* __restrict__ A, const short* __restrict__ Bt,
    const float* __restrict__ bias, int M, int N, int K, int mode,
    short* __restrict__ qout, short* __restrict__ kout,
    short* __restrict__ vout, float* __restrict__ fout) {
  __shared__ short As[128 * 32];
  __shared__ short Bs[128 * 32];
  const int tid = threadIdx.x;
  const int l = tid & 63, w = tid >> 6;
  const int lr = l & 15, g = l >> 4;
  const int bm = blockIdx.y * 128, bn = blockIdx.x * 128;
  const int wm = w >> 1, wn = w & 1;

  f32x4 acc[4][4];
  const f32x4 z4 = {0.f, 0.f, 0.f, 0.f};
#pragma unroll
  for (int m = 0; m < 4; ++m)
#pragma unroll
    for (int n = 0; n < 4; ++n) acc[m][n] = z4;

  for (int k0 = 0; k0 < K; k0 += 32) {
    __syncthreads();
#pragma unroll
    for (int it = 0; it < 2; ++it) {
      int row = w * 16 + lr + 64 * it;
      s16x8 va = *(const s16x8*)(A + (size_t)(bm + row) * K + k0 + g * 8);
      s16x8 vb = *(const s16x8*)(Bt + (size_t)(bn + row) * K + k0 + g * 8);
      int byte = (row * 64 + g * 16) ^ ((((unsigned)row >> 1) & 7) << 4);
      *(s16x8*)((char*)As + byte) = va;
      *(s16x8*)((char*)Bs + byte) = vb;
    }
    __syncthreads();
    s16x8 af[4], bfr[4];
#pragma unroll
    for (int m = 0; m < 4; ++m) {
      int row = wm * 64 + m * 16 + lr;
      int byte = (row * 64 + g * 16) ^ ((((unsigned)row >> 1) & 7) << 4);
      af[m] = *(const s16x8*)((char*)As + byte);
    }
#pragma unroll
    for (int n = 0; n < 4; ++n) {
      int row = wn * 64 + n * 16 + lr;
      int byte = (row * 64 + g * 16) ^ ((((unsigned)row >> 1) & 7) << 4);
      bfr[n] = *(const s16x8*)((char*)Bs + byte);
    }
#pragma unroll
    for (int m = 0; m < 4; ++m)
#pragma unroll
      for (int n = 0; n < 4; ++n)
        acc[m][n] = __builtin_amdgcn_mfma_f32_16x16x32_bf16(af[m], bfr[n],
                                                            acc[m][n], 0, 0, 0);
  }

#pragma unroll
  for (int m = 0; m < 4; ++m) {
    int rbase = bm + wm * 64 + m * 16 + g * 4;
#pragma unroll
    for (int n = 0; n < 4; ++n) {
      int col = bn + wn * 64 + n * 16 + lr;
      float bv = bias[col];
      if (mode == 0) {
        int which = (col >= 1536) ? 2 : (col >= 768 ? 1 : 0);
        int rem = col - which * 768;
        int h = rem >> 6, d = rem & 63;
#pragma unroll
        for (int i = 0; i < 4; ++i) {
          int r = rbase + i;
          int b = r >> 11, s = r & 2047;
          short o = f2b(acc[m][n][i] + bv);
          size_t bh = (size_t)b * HDIM + h;
          if (which == 0)      qout[(bh * SDIM + s) * DDIM + d] = o;
          else if (which == 1) kout[(bh * SDIM + s) * DDIM + d] = o;
          else                 vout[(bh * DDIM + d) * SDIM + s] = o;  // V transposed
        }
      } else {
#pragma unroll
        for (int i = 0; i < 4; ++i)
          fout[(size_t)(rbase + i) * N + col] = acc[m][n][i] + bv;
      }
    }
  }
}

// ---------------- flash attention v3: paired tiles, glds 2-phase, swapped MFMA
// qb,kb: [BH][S][D] bf16 ; vb: [BH][D][S] bf16 ; ao: [B*S][E] bf16
// Block = 4 waves; handles q-tiles (31-p) then (p): 33 kt-steps for every block.
// Swapped operands: S and O both have col = q-row = lane (softmax lane-local).
__global__ __launch_bounds__(256) void attn_mfma3(
    const short* __restrict__ qb, const short* __restrict__ kb,
    const short* __restrict__ vb, short* __restrict__ ao) {
  __shared__ short kvbuf[2][8192];   // [buf][ K 64x64 | V 64x64 ] bf16, swizzled
  __shared__ short pstrip[4][1024];  // per-wave P[16 qrow][64 key] bf16, swizzled

  const int tid = threadIdx.x;
  const int l = tid & 63, w = tid >> 6;
  const int lr = l & 15, g = l >> 4;
  const int swz = (lr & 7) << 4;

  // XCD-affine decode: each XCD (blockIdx%8) owns 6 complete heads
  const int lin = blockIdx.x;
  const int xcd = lin & 7;
  const int idx = lin >> 3;            // 0..95
  const int bh = xcd * 6 + (idx >> 4); // 0..47
  const int pair = idx & 15;
  const int tiles[2] = {NTILE - 1 - pair, pair};

  const int b = bh / HDIM, h = bh % HDIM;
  const size_t base = (size_t)bh * SDIM * DDIM;

  // staging geometry: lane covers LDS byte w*2048 + it*1024 + l*16
  const int srow = w * 16 + (l >> 3);        // rows srow, srow+8 (it=0,1)
  const int sc = (l & 7) ^ (srow & 7);       // pre-swizzled source chunk
  const size_t koff0 = (size_t)srow * DDIM + sc * 8;
  const size_t koff1 = (size_t)(srow + 8) * DDIM + sc * 8;
  const size_t voff0 = (size_t)srow * SDIM + sc * 8;
  const size_t voff1 = (size_t)(srow + 8) * SDIM + sc * 8;

  const float SC = 0.125f * 1.4426950408889634f;  // scale * log2(e)
  char* sw = (char*)pstrip[w];

  for (int half = 0; half < 2; ++half) {
    const int tile = tiles[half];
    const int q0w = tile * 64 + w * 16;

    // Q fragments (B-operand of swapped QK = same data as A-frag of Q)
    s16x8 qa[2];
#pragma unroll
    for (int s = 0; s < 2; ++s)
      qa[s] = *(const s16x8*)(qb + base + (size_t)(q0w + lr) * DDIM + s * 32 + g * 8);

    const f32x4 z4 = {0.f, 0.f, 0.f, 0.f};
    f32x4 acco[4];
#pragma unroll
    for (int nd = 0; nd < 4; ++nd) acco[nd] = z4;
    float mrun = -1e30f, lsum = 0.f;

    int cur = 0;
    // prologue: stage kt=0
    {
      char* kd = (char*)kvbuf[cur] + w * 2048;
      const short* kp = kb + base;
      const short* vp = vb + base;
      gld16(kp + koff0, kd);
      gld16(kp + koff1, kd + 1024);
      gld16(vp + voff0, kd + 8192);
      gld16(vp + voff1, kd + 9216);
    }
    __syncthreads();

    for (int kt = 0; kt <= tile; ++kt) {
      // 2-phase: stage kt+1 into the other buffer while computing kt
      if (kt < tile) {
        char* kd = (char*)kvbuf[cur ^ 1] + w * 2048;
        const short* kp = kb + base + (size_t)(kt + 1) * 64 * DDIM;
        const short* vp = vb + base + (size_t)(kt + 1) * 64;
        gld16(kp + koff0, kd);
        gld16(kp + koff1, kd + 1024);
        gld16(vp + voff0, kd + 8192);
        gld16(vp + voff1, kd + 9216);
      }

      const char* Kb = (const char*)kvbuf[cur];
      const char* Vb = Kb + 8192;

      // S = K Q  (swapped): sacc[nt][i] = S[key nt*16+g*4+i][qrow lr]
      f32x4 sacc[4];
#pragma unroll
      for (int nt = 0; nt < 4; ++nt) sacc[nt] = z4;
      __builtin_amdgcn_s_setprio(1);
#pragma unroll
      for (int s = 0; s < 2; ++s)
#pragma unroll
        for (int nt = 0; nt < 4; ++nt) {
          s16x8 kf = *(const s16x8*)(Kb + nt * 2048 + lr * 128 +
                                     ((s * 64 + g * 16) ^ swz));
          sacc[nt] = __builtin_amdgcn_mfma_f32_16x16x32_bf16(kf, qa[s],
                                                             sacc[nt], 0, 0, 0);
        }
      __builtin_amdgcn_s_setprio(0);

      // causal mask only on the diagonal tile
      if (kt == tile) {
        const int rloc = w * 16 + lr;
#pragma unroll
        for (int nt = 0; nt < 4; ++nt)
#pragma unroll
          for (int i = 0; i < 4; ++i)
            if (nt * 16 + g * 4 + i > rloc) sacc[nt][i] = -1e30f;
      }

      // row max: 15 in-lane + 2 shuffle rounds (g dimension)
      float pmax = -1e30f;
#pragma unroll
      for (int nt = 0; nt < 4; ++nt)
#pragma unroll
        for (int i = 0; i < 4; ++i) pmax = fmaxf(pmax, sacc[nt][i]);
      pmax = fmaxf(pmax, __shfl_xor(pmax, 16, 64));
      pmax = fmaxf(pmax, __shfl_xor(pmax, 32, 64));

      // defer-rescale (raw-domain threshold 44 ~ exp2 bound 2^8)
      if (__any(pmax > mrun + 44.0f)) {
        float nm = fmaxf(mrun, pmax);
        float al = exp2f((mrun - nm) * SC);
        lsum *= al;
#pragma unroll
        for (int nd = 0; nd < 4; ++nd)
#pragma unroll
          for (int i = 0; i < 4; ++i) acco[nd][i] *= al;
        mrun = nm;
      }

      // P = exp2(S*SC - m*SC), packed bf16 -> per-wave strip (b64 writes)
      const float msc = mrun * SC;
#pragma unroll
      for (int nt = 0; nt < 4; ++nt) {
        float p0 = exp2f(__builtin_fmaf(sacc[nt][0], SC, -msc));
        float p1 = exp2f(__builtin_fmaf(sacc[nt][1], SC, -msc));
        float p2 = exp2f(__builtin_fmaf(sacc[nt][2], SC, -msc));
        float p3 = exp2f(__builtin_fmaf(sacc[nt][3], SC, -msc));
        lsum += (p0 + p1) + (p2 + p3);
        u32x2 pk = {cvtpk(p0, p1), cvtpk(p2, p3)};
        *(u32x2*)(sw + lr * 128 + (((nt * 32 + g * 8) ^ swz))) = pk;
      }

      // O += V^T P (swapped): acco[nd][i] = O[d nd*16+g*4+i][qrow lr]
      __builtin_amdgcn_s_setprio(1);
#pragma unroll
      for (int s = 0; s < 2; ++s) {
        s16x8 pf = *(const s16x8*)(sw + lr * 128 + ((s * 64 + g * 16) ^ swz));
#pragma unroll
        for (int nd = 0; nd < 4; ++nd) {
          s16x8 vf = *(const s16x8*)(Vb + nd * 2048 + lr * 128 +
                                     ((s * 64 + g * 16) ^ swz));
          acco[nd] = __builtin_amdgcn_mfma_f32_16x16x32_bf16(vf, pf,
                                                             acco[nd], 0, 0, 0);
        }
      }
      __builtin_amdgcn_s_setprio(0);

      __syncthreads();   // drains vmcnt (glds) + lgkm; next buffer ready
      cur ^= 1;
    }

    // final l reduce (lane partials over g), normalize, store packed pairs
    lsum += __shfl_xor(lsum, 16, 64);
    lsum += __shfl_xor(lsum, 32, 64);
    float inv = 1.0f / lsum;
    size_t orow = ((size_t)b * SDIM + q0w + lr) * EDIM + h * DDIM;
#pragma unroll
    for (int nd = 0; nd < 4; ++nd) {
      unsigned lo = cvtpk(acco[nd][0] * inv, acco[nd][1] * inv);
      unsigned hi = cvtpk(acco[nd][2] * inv, acco[nd][3] * inv);
      *(unsigned*)(ao + orow + nd * 16 + g * 4) = lo;
      *(unsigned*)(ao + orow + nd * 16 + g * 4 + 2) = hi;
    }
  }
}

extern "C" void kernel_launch(void* const* d_in, const int* in_sizes, int n_in,
                              void* d_out, int out_size, void* d_ws,
                              size_t ws_size, hipStream_t stream) {
  const float* x = (const float*)d_in[0];
  const float* w_qkv = (const float*)d_in[1];
  const float* b_qkv = (const float*)d_in[2];
  const float* w_proj = (const float*)d_in[3];
  const float* b_proj = (const float*)d_in[4];
  float* out = (float*)d_out;

  char* p = (char*)d_ws;
  short* xb = (short*)p;      p += (size_t)MROWS * EDIM * 2;
  short* wqkvt = (short*)p;   p += (size_t)NQKV * EDIM * 2;
  short* wprojt = (short*)p;  p += (size_t)EDIM * EDIM * 2;
  short* qbuf = (short*)p;    p += (size_t)NBH * SDIM * DDIM * 2;
  short* kbuf = (short*)p;    p += (size_t)NBH * SDIM * DDIM * 2;
  short* vbuf = (short*)p;    p += (size_t)NBH * SDIM * DDIM * 2;
  short* aob = (short*)p;     p += (size_t)MROWS * EDIM * 2;

  dim3 blk(256);
  convert_bf16<<<dim3(2048), blk, 0, stream>>>(x, xb, MROWS * EDIM / 4);
  transpose_bf16<<<dim3(NQKV / 32, EDIM / 32), blk, 0, stream>>>(w_qkv, wqkvt, EDIM, NQKV);
  transpose_bf16<<<dim3(EDIM / 32, EDIM / 32), blk, 0, stream>>>(w_proj, wprojt, EDIM, EDIM);
  gemm_bf16<<<dim3(NQKV / 128, MROWS / 128), blk, 0, stream>>>(
      xb, wqkvt, b_qkv, MROWS, NQKV, EDIM, 0, qbuf, kbuf, vbuf, nullptr);
  attn_mfma3<<<dim3(NPAIR * NBH), blk, 0, stream>>>(qbuf, kbuf, vbuf, aob);
  gemm_bf16<<<dim3(EDIM / 128, MROWS / 128), blk, 0, stream>>>(
      aob, wprojt, b_proj, MROWS, EDIM, EDIM, 1, nullptr, nullptr, nullptr, out);
}

// Round 5
// 165.167 us; speedup vs baseline: 2.2992x; 1.2084x over previous
//
#include <hip/hip_runtime.h>

#define SDIM 2048
#define EDIM 768
#define HDIM 12
#define DDIM 64
#define BDIM 4
#define MROWS (BDIM * SDIM)   // 8192
#define NQKV (3 * EDIM)       // 2304
#define NBH (BDIM * HDIM)     // 48
#define NTILE 32              // 2048 / 64 q-tiles
#define NPAIR 16

typedef __attribute__((ext_vector_type(8))) short s16x8;   // 8 bf16
typedef __attribute__((ext_vector_type(4))) float f32x4;
typedef __attribute__((ext_vector_type(2))) unsigned int u32x2;

__device__ __forceinline__ short f2b(float x) {
  union { float f; unsigned u; } v; v.f = x;
  unsigned r = v.u + 0x7fffu + ((v.u >> 16) & 1u);
  return (short)(r >> 16);
}

__device__ __forceinline__ unsigned cvtpk(float lo, float hi) {
  unsigned r;
  asm volatile("v_cvt_pk_bf16_f32 %0, %1, %2" : "=v"(r) : "v"(lo), "v"(hi));
  return r;
}

__device__ __forceinline__ void gld16(const void* g, void* l) {
  __builtin_amdgcn_global_load_lds(
      (const __attribute__((address_space(1))) unsigned int*)g,
      (__attribute__((address_space(3))) unsigned int*)l, 16, 0, 0);
}

// ---------------- elementwise fp32 -> bf16 ----------------
__global__ __launch_bounds__(256) void convert_bf16(
    const float* __restrict__ in, short* __restrict__ out, int n4) {
  int i = blockIdx.x * 256 + threadIdx.x;
  int stride = gridDim.x * 256;
  for (; i < n4; i += stride) {
    float4 v = ((const float4*)in)[i];
    short4 o;
    o.x = f2b(v.x); o.y = f2b(v.y); o.z = f2b(v.z); o.w = f2b(v.w);
    ((short4*)out)[i] = o;
  }
}

// ---------------- transpose + convert: [K][N] f32 -> [N][K] bf16 ----------------
__global__ __launch_bounds__(256) void transpose_bf16(
    const float* __restrict__ in, short* __restrict__ out, int K, int N) {
  __shared__ float t[32][33];
  int n0 = blockIdx.x * 32, k0 = blockIdx.y * 32;
  int tx = threadIdx.x & 31, ty = threadIdx.x >> 5;  // ty 0..7
#pragma unroll
  for (int i = 0; i < 4; ++i)
    t[ty + 8 * i][tx] = in[(size_t)(k0 + ty + 8 * i) * N + n0 + tx];
  __syncthreads();
#pragma unroll
  for (int i = 0; i < 4; ++i)
    out[(size_t)(n0 + ty + 8 * i) * K + k0 + tx] = f2b(t[tx][ty + 8 * i]);
}

// ---------------- bf16 MFMA GEMM v2 ----------------
// 128x128 tile, BK=32, 4 waves, double-buffered LDS staged via
// global_load_lds width-16 (linear dest + source pre-swizzle, XOR (row>>1)&3).
// T3-minimum pipeline: STAGE(next) issued before compute(cur), 1 barrier/iter.
__global__ __launch_bounds__(256) void gemm_bf16(
    const short* __restrict__ A, const short* __restrict__ Bt,
    const float* __restrict__ bias, int M, int N, int K, int mode,
    short* __restrict__ qout, short* __restrict__ kout,
    short* __restrict__ vout, float* __restrict__ fout) {
  __shared__ char lds[2][16384];  // [buf][ A 128x32 | B 128x32 ] bf16
  const int tid = threadIdx.x;
  const int l = tid & 63, w = tid >> 6;
  const int lr = l & 15, g = l >> 4;
  const int bm = blockIdx.y * 128, bn = blockIdx.x * 128;
  const int wm = w >> 1, wn = w & 1;

  // staging geometry: wave w covers rows w*32..w*32+31 (2 chunks of 16 rows)
  const int srow = w * 32 + (l >> 2);                    // + 0 / +16
  const int sc8 = (((l & 3) ^ ((l >> 3) & 3)) << 3);     // pre-swizzled k-elem
  const short* Ap0 = A + (size_t)(bm + srow) * K + sc8;
  const short* Bp0 = Bt + (size_t)(bn + srow) * K + sc8;

  f32x4 acc[4][4];
  const f32x4 z4 = {0.f, 0.f, 0.f, 0.f};
#pragma unroll
  for (int m = 0; m < 4; ++m)
#pragma unroll
    for (int n = 0; n < 4; ++n) acc[m][n] = z4;

  const int nt = K >> 5;  // 24
  // prologue: stage tile 0 into buf 0
  {
    char* Ad = lds[0] + w * 2048;
    gld16(Ap0, Ad);
    gld16(Ap0 + 16 * K, Ad + 1024);
    gld16(Bp0, Ad + 8192);
    gld16(Bp0 + 16 * K, Ad + 9216);
  }
  __syncthreads();

  const int swz = ((lr >> 1) & 3) << 4;
  int buf = 0;
  for (int t = 0; t < nt; ++t) {
    if (t + 1 < nt) {  // stage next tile into other buffer (loads fly over compute)
      char* Ad = lds[buf ^ 1] + w * 2048;
      const short* Ap = Ap0 + (t + 1) * 32;
      const short* Bp = Bp0 + (t + 1) * 32;
      gld16(Ap, Ad);
      gld16(Ap + 16 * K, Ad + 1024);
      gld16(Bp, Ad + 8192);
      gld16(Bp + 16 * K, Ad + 9216);
    }
    const char* Ab = lds[buf];
    const char* Bb = lds[buf] + 8192;
    s16x8 af[4], bfr[4];
#pragma unroll
    for (int m = 0; m < 4; ++m)
      af[m] = *(const s16x8*)(Ab + (wm * 64 + m * 16 + lr) * 64 + ((g << 4) ^ swz));
#pragma unroll
    for (int n = 0; n < 4; ++n)
      bfr[n] = *(const s16x8*)(Bb + (wn * 64 + n * 16 + lr) * 64 + ((g << 4) ^ swz));
#pragma unroll
    for (int m = 0; m < 4; ++m)
#pragma unroll
      for (int n = 0; n < 4; ++n)
        acc[m][n] = __builtin_amdgcn_mfma_f32_16x16x32_bf16(af[m], bfr[n],
                                                            acc[m][n], 0, 0, 0);
    __syncthreads();  // drains glds (next buf ready) + all reads of cur done
    buf ^= 1;
  }

#pragma unroll
  for (int m = 0; m < 4; ++m) {
    int rbase = bm + wm * 64 + m * 16 + g * 4;
#pragma unroll
    for (int n = 0; n < 4; ++n) {
      int col = bn + wn * 64 + n * 16 + lr;
      float bv = bias[col];
      if (mode == 0) {
        int which = (col >= 1536) ? 2 : (col >= 768 ? 1 : 0);
        int rem = col - which * 768;
        int h = rem >> 6, d = rem & 63;
#pragma unroll
        for (int i = 0; i < 4; ++i) {
          int r = rbase + i;
          int b = r >> 11, s = r & 2047;
          short o = f2b(acc[m][n][i] + bv);
          size_t bh = (size_t)b * HDIM + h;
          if (which == 0)      qout[(bh * SDIM + s) * DDIM + d] = o;
          else if (which == 1) kout[(bh * SDIM + s) * DDIM + d] = o;
          else                 vout[(bh * DDIM + d) * SDIM + s] = o;  // V transposed
        }
      } else {
#pragma unroll
        for (int i = 0; i < 4; ++i)
          fout[(size_t)(rbase + i) * N + col] = acc[m][n][i] + bv;
      }
    }
  }
}

// ---------------- flash attention v3: paired tiles, glds 2-phase, swapped MFMA
// qb,kb: [BH][S][D] bf16 ; vb: [BH][D][S] bf16 ; ao: [B*S][E] bf16
__global__ __launch_bounds__(256) void attn_mfma3(
    const short* __restrict__ qb, const short* __restrict__ kb,
    const short* __restrict__ vb, short* __restrict__ ao) {
  __shared__ short kvbuf[2][8192];   // [buf][ K 64x64 | V 64x64 ] bf16, swizzled
  __shared__ short pstrip[4][1024];  // per-wave P[16 qrow][64 key] bf16, swizzled

  const int tid = threadIdx.x;
  const int l = tid & 63, w = tid >> 6;
  const int lr = l & 15, g = l >> 4;
  const int swz = (lr & 7) << 4;

  const int lin = blockIdx.x;
  const int xcd = lin & 7;
  const int idx = lin >> 3;            // 0..95
  const int bh = xcd * 6 + (idx >> 4); // 0..47
  const int pair = idx & 15;
  const int tiles[2] = {NTILE - 1 - pair, pair};

  const int b = bh / HDIM, h = bh % HDIM;
  const size_t base = (size_t)bh * SDIM * DDIM;

  const int srow = w * 16 + (l >> 3);        // rows srow, srow+8 (it=0,1)
  const int sc = (l & 7) ^ (srow & 7);       // pre-swizzled source chunk
  const size_t koff0 = (size_t)srow * DDIM + sc * 8;
  const size_t koff1 = (size_t)(srow + 8) * DDIM + sc * 8;
  const size_t voff0 = (size_t)srow * SDIM + sc * 8;
  const size_t voff1 = (size_t)(srow + 8) * SDIM + sc * 8;

  const float SC = 0.125f * 1.4426950408889634f;  // scale * log2(e)
  char* sw = (char*)pstrip[w];

  for (int half = 0; half < 2; ++half) {
    const int tile = tiles[half];
    const int q0w = tile * 64 + w * 16;

    s16x8 qa[2];
#pragma unroll
    for (int s = 0; s < 2; ++s)
      qa[s] = *(const s16x8*)(qb + base + (size_t)(q0w + lr) * DDIM + s * 32 + g * 8);

    const f32x4 z4 = {0.f, 0.f, 0.f, 0.f};
    f32x4 acco[4];
#pragma unroll
    for (int nd = 0; nd < 4; ++nd) acco[nd] = z4;
    float mrun = -1e30f, lsum = 0.f;

    int cur = 0;
    {
      char* kd = (char*)kvbuf[cur] + w * 2048;
      const short* kp = kb + base;
      const short* vp = vb + base;
      gld16(kp + koff0, kd);
      gld16(kp + koff1, kd + 1024);
      gld16(vp + voff0, kd + 8192);
      gld16(vp + voff1, kd + 9216);
    }
    __syncthreads();

    for (int kt = 0; kt <= tile; ++kt) {
      if (kt < tile) {
        char* kd = (char*)kvbuf[cur ^ 1] + w * 2048;
        const short* kp = kb + base + (size_t)(kt + 1) * 64 * DDIM;
        const short* vp = vb + base + (size_t)(kt + 1) * 64;
        gld16(kp + koff0, kd);
        gld16(kp + koff1, kd + 1024);
        gld16(vp + voff0, kd + 8192);
        gld16(vp + voff1, kd + 9216);
      }

      const char* Kb = (const char*)kvbuf[cur];
      const char* Vb = Kb + 8192;

      f32x4 sacc[4];
#pragma unroll
      for (int nt = 0; nt < 4; ++nt) sacc[nt] = z4;
      __builtin_amdgcn_s_setprio(1);
#pragma unroll
      for (int s = 0; s < 2; ++s)
#pragma unroll
        for (int nt = 0; nt < 4; ++nt) {
          s16x8 kf = *(const s16x8*)(Kb + nt * 2048 + lr * 128 +
                                     ((s * 64 + g * 16) ^ swz));
          sacc[nt] = __builtin_amdgcn_mfma_f32_16x16x32_bf16(kf, qa[s],
                                                             sacc[nt], 0, 0, 0);
        }
      __builtin_amdgcn_s_setprio(0);

      if (kt == tile) {
        const int rloc = w * 16 + lr;
#pragma unroll
        for (int nt = 0; nt < 4; ++nt)
#pragma unroll
          for (int i = 0; i < 4; ++i)
            if (nt * 16 + g * 4 + i > rloc) sacc[nt][i] = -1e30f;
      }

      float pmax = -1e30f;
#pragma unroll
      for (int nt = 0; nt < 4; ++nt)
#pragma unroll
        for (int i = 0; i < 4; ++i) pmax = fmaxf(pmax, sacc[nt][i]);
      pmax = fmaxf(pmax, __shfl_xor(pmax, 16, 64));
      pmax = fmaxf(pmax, __shfl_xor(pmax, 32, 64));

      if (__any(pmax > mrun + 44.0f)) {
        float nm = fmaxf(mrun, pmax);
        float al = exp2f((mrun - nm) * SC);
        lsum *= al;
#pragma unroll
        for (int nd = 0; nd < 4; ++nd)
#pragma unroll
          for (int i = 0; i < 4; ++i) acco[nd][i] *= al;
        mrun = nm;
      }

      const float msc = mrun * SC;
#pragma unroll
      for (int nt = 0; nt < 4; ++nt) {
        float p0 = exp2f(__builtin_fmaf(sacc[nt][0], SC, -msc));
        float p1 = exp2f(__builtin_fmaf(sacc[nt][1], SC, -msc));
        float p2 = exp2f(__builtin_fmaf(sacc[nt][2], SC, -msc));
        float p3 = exp2f(__builtin_fmaf(sacc[nt][3], SC, -msc));
        lsum += (p0 + p1) + (p2 + p3);
        u32x2 pk = {cvtpk(p0, p1), cvtpk(p2, p3)};
        *(u32x2*)(sw + lr * 128 + (((nt * 32 + g * 8) ^ swz))) = pk;
      }

      __builtin_amdgcn_s_setprio(1);
#pragma unroll
      for (int s = 0; s < 2; ++s) {
        s16x8 pf = *(const s16x8*)(sw + lr * 128 + ((s * 64 + g * 16) ^ swz));
#pragma unroll
        for (int nd = 0; nd < 4; ++nd) {
          s16x8 vf = *(const s16x8*)(Vb + nd * 2048 + lr * 128 +
                                     ((s * 64 + g * 16) ^ swz));
          acco[nd] = __builtin_amdgcn_mfma_f32_16x16x32_bf16(vf, pf,
                                                             acco[nd], 0, 0, 0);
        }
      }
      __builtin_amdgcn_s_setprio(0);

      __syncthreads();
      cur ^= 1;
    }

    lsum += __shfl_xor(lsum, 16, 64);
    lsum += __shfl_xor(lsum, 32, 64);
    float inv = 1.0f / lsum;
    size_t orow = ((size_t)b * SDIM + q0w + lr) * EDIM + h * DDIM;
#pragma unroll
    for (int nd = 0; nd < 4; ++nd) {
      unsigned lo = cvtpk(acco[nd][0] * inv, acco[nd][1] * inv);
      unsigned hi = cvtpk(acco[nd][2] * inv, acco[nd][3] * inv);
      *(unsigned*)(ao + orow + nd * 16 + g * 4) = lo;
      *(unsigned*)(ao + orow + nd * 16 + g * 4 + 2) = hi;
    }
  }
}

extern "C" void kernel_launch(void* const* d_in, const int* in_sizes, int n_in,
                              void* d_out, int out_size, void* d_ws,
                              size_t ws_size, hipStream_t stream) {
  const float* x = (const float*)d_in[0];
  const float* w_qkv = (const float*)d_in[1];
  const float* b_qkv = (const float*)d_in[2];
  const float* w_proj = (const float*)d_in[3];
  const float* b_proj = (const float*)d_in[4];
  float* out = (float*)d_out;

  char* p = (char*)d_ws;
  short* xb = (short*)p;      p += (size_t)MROWS * EDIM * 2;
  short* wqkvt = (short*)p;   p += (size_t)NQKV * EDIM * 2;
  short* wprojt = (short*)p;  p += (size_t)EDIM * EDIM * 2;
  short* qbuf = (short*)p;    p += (size_t)NBH * SDIM * DDIM * 2;
  short* kbuf = (short*)p;    p += (size_t)NBH * SDIM * DDIM * 2;
  short* vbuf = (short*)p;    p += (size_t)NBH * SDIM * DDIM * 2;
  short* aob = (short*)p;     p += (size_t)MROWS * EDIM * 2;

  dim3 blk(256);
  convert_bf16<<<dim3(2048), blk, 0, stream>>>(x, xb, MROWS * EDIM / 4);
  transpose_bf16<<<dim3(NQKV / 32, EDIM / 32), blk, 0, stream>>>(w_qkv, wqkvt, EDIM, NQKV);
  transpose_bf16<<<dim3(EDIM / 32, EDIM / 32), blk, 0, stream>>>(w_proj, wprojt, EDIM, EDIM);
  gemm_bf16<<<dim3(NQKV / 128, MROWS / 128), blk, 0, stream>>>(
      xb, wqkvt, b_qkv, MROWS, NQKV, EDIM, 0, qbuf, kbuf, vbuf, nullptr);
  attn_mfma3<<<dim3(NPAIR * NBH), blk, 0, stream>>>(qbuf, kbuf, vbuf, aob);
  gemm_bf16<<<dim3(EDIM / 128, MROWS / 128), blk, 0, stream>>>(
      aob, wprojt, b_proj, MROWS, EDIM, EDIM, 1, nullptr, nullptr, nullptr, out);
}

// Round 6
// 151.117 us; speedup vs baseline: 2.5130x; 1.0930x over previous
//
#include <hip/hip_runtime.h>

#define SDIM 2048
#define EDIM 768
#define HDIM 12
#define DDIM 64
#define BDIM 4
#define MROWS (BDIM * SDIM)   // 8192
#define NQKV (3 * EDIM)       // 2304
#define NBH (BDIM * HDIM)     // 48
#define NTILE 32              // 2048 / 64 q-tiles
#define NPAIR 16

typedef __attribute__((ext_vector_type(8))) short s16x8;   // 8 bf16
typedef __attribute__((ext_vector_type(4))) float f32x4;
typedef __attribute__((ext_vector_type(2))) unsigned int u32x2;

__device__ __forceinline__ short f2b(float x) {
  union { float f; unsigned u; } v; v.f = x;
  unsigned r = v.u + 0x7fffu + ((v.u >> 16) & 1u);
  return (short)(r >> 16);
}

__device__ __forceinline__ unsigned cvtpk(float lo, float hi) {
  unsigned r;
  asm volatile("v_cvt_pk_bf16_f32 %0, %1, %2" : "=v"(r) : "v"(lo), "v"(hi));
  return r;
}

// bare v_exp_f32 (2^x). CDNA scoreboards trans-op results in HW.
__device__ __forceinline__ float fexp2(float x) {
  float r;
  asm("v_exp_f32 %0, %1" : "=v"(r) : "v"(x));
  return r;
}

__device__ __forceinline__ void gld16(const void* g, void* l) {
  __builtin_amdgcn_global_load_lds(
      (const __attribute__((address_space(1))) unsigned int*)g,
      (__attribute__((address_space(3))) unsigned int*)l, 16, 0, 0);
}

// ---------------- elementwise fp32 -> bf16 ----------------
__global__ __launch_bounds__(256) void convert_bf16(
    const float* __restrict__ in, short* __restrict__ out, int n4) {
  int i = blockIdx.x * 256 + threadIdx.x;
  int stride = gridDim.x * 256;
  for (; i < n4; i += stride) {
    float4 v = ((const float4*)in)[i];
    short4 o;
    o.x = f2b(v.x); o.y = f2b(v.y); o.z = f2b(v.z); o.w = f2b(v.w);
    ((short4*)out)[i] = o;
  }
}

// ---------------- transpose + convert: [K][N] f32 -> [N][K] bf16 ----------------
__global__ __launch_bounds__(256) void transpose_bf16(
    const float* __restrict__ in, short* __restrict__ out, int K, int N) {
  __shared__ float t[32][33];
  int n0 = blockIdx.x * 32, k0 = blockIdx.y * 32;
  int tx = threadIdx.x & 31, ty = threadIdx.x >> 5;  // ty 0..7
#pragma unroll
  for (int i = 0; i < 4; ++i)
    t[ty + 8 * i][tx] = in[(size_t)(k0 + ty + 8 * i) * N + n0 + tx];
  __syncthreads();
#pragma unroll
  for (int i = 0; i < 4; ++i)
    out[(size_t)(n0 + ty + 8 * i) * K + k0 + tx] = f2b(t[tx][ty + 8 * i]);
}

// ---------------- bf16 MFMA GEMM v3 ----------------
// 128x128 tile, BK=32, 4 waves, TRIPLE-buffered LDS via global_load_lds w16,
// counted s_waitcnt vmcnt(4) before barrier (T4): next-tile loads stay in
// flight across the barrier; vmcnt(0) only in the 2-iter drain tail.
__global__ __launch_bounds__(256) void gemm_bf16(
    const short* __restrict__ A, const short* __restrict__ Bt,
    const float* __restrict__ bias, int M, int N, int K, int mode,
    short* __restrict__ qout, short* __restrict__ kout,
    short* __restrict__ vout, float* __restrict__ fout) {
  __shared__ char lds[3][16384];  // [buf][ A 128x32 | B 128x32 ] bf16
  const int tid = threadIdx.x;
  const int l = tid & 63, w = tid >> 6;
  const int lr = l & 15, g = l >> 4;
  const int bm = blockIdx.y * 128, bn = blockIdx.x * 128;
  const int wm = w >> 1, wn = w & 1;

  // staging geometry: wave w covers rows w*32..w*32+31 (2 chunks of 16 rows)
  const int srow = w * 32 + (l >> 2);                    // + 0 / +16
  const int sc8 = (((l & 3) ^ ((l >> 3) & 3)) << 3);     // pre-swizzled k-elem
  const short* Ap0 = A + (size_t)(bm + srow) * K + sc8;
  const short* Bp0 = Bt + (size_t)(bn + srow) * K + sc8;

  f32x4 acc[4][4];
  const f32x4 z4 = {0.f, 0.f, 0.f, 0.f};
#pragma unroll
  for (int m = 0; m < 4; ++m)
#pragma unroll
    for (int n = 0; n < 4; ++n) acc[m][n] = z4;

#define STAGE(dst, t)                          \
  {                                            \
    char* Ad = (dst) + w * 2048;               \
    const short* Ap = Ap0 + (t) * 32;          \
    const short* Bp = Bp0 + (t) * 32;          \
    gld16(Ap, Ad);                             \
    gld16(Ap + 16 * K, Ad + 1024);             \
    gld16(Bp, Ad + 8192);                      \
    gld16(Bp + 16 * K, Ad + 9216);             \
  }

  const int nt = K >> 5;  // 24
  // prologue: stage tiles 0 and 1; wait only for tile 0 (vmcnt(4))
  STAGE(lds[0], 0);
  STAGE(lds[1], 1);
  asm volatile("s_waitcnt vmcnt(4)" ::: "memory");
  __builtin_amdgcn_s_barrier();

  const int swz = ((lr >> 1) & 3) << 4;
  int bc = 0;  // compute buffer = t % 3
  for (int t = 0; t < nt; ++t) {
    if (t + 2 < nt) {
      int bs = bc + 2; if (bs >= 3) bs -= 3;
      STAGE(lds[bs], t + 2);
    }
    const char* Ab = lds[bc];
    const char* Bb = lds[bc] + 8192;
    s16x8 af[4], bfr[4];
#pragma unroll
    for (int m = 0; m < 4; ++m)
      af[m] = *(const s16x8*)(Ab + (wm * 64 + m * 16 + lr) * 64 + ((g << 4) ^ swz));
#pragma unroll
    for (int n = 0; n < 4; ++n)
      bfr[n] = *(const s16x8*)(Bb + (wn * 64 + n * 16 + lr) * 64 + ((g << 4) ^ swz));
#pragma unroll
    for (int m = 0; m < 4; ++m)
#pragma unroll
      for (int n = 0; n < 4; ++n)
        acc[m][n] = __builtin_amdgcn_mfma_f32_16x16x32_bf16(af[m], bfr[n],
                                                            acc[m][n], 0, 0, 0);
    // counted wait: tile t+1's 4 loads landed; this iter's 4 keep flying
    if (t + 2 < nt) {
      asm volatile("s_waitcnt vmcnt(4)" ::: "memory");
      __builtin_amdgcn_s_barrier();
    } else if (t + 1 < nt) {
      asm volatile("s_waitcnt vmcnt(0)" ::: "memory");
      __builtin_amdgcn_s_barrier();
    }
    if (++bc == 3) bc = 0;
  }
#undef STAGE

#pragma unroll
  for (int m = 0; m < 4; ++m) {
    int rbase = bm + wm * 64 + m * 16 + g * 4;
#pragma unroll
    for (int n = 0; n < 4; ++n) {
      int col = bn + wn * 64 + n * 16 + lr;
      float bv = bias[col];
      if (mode == 0) {
        int which = (col >= 1536) ? 2 : (col >= 768 ? 1 : 0);
        int rem = col - which * 768;
        int h = rem >> 6, d = rem & 63;
#pragma unroll
        for (int i = 0; i < 4; ++i) {
          int r = rbase + i;
          int b = r >> 11, s = r & 2047;
          short o = f2b(acc[m][n][i] + bv);
          size_t bh = (size_t)b * HDIM + h;
          if (which == 0)      qout[(bh * SDIM + s) * DDIM + d] = o;
          else if (which == 1) kout[(bh * SDIM + s) * DDIM + d] = o;
          else                 vout[(bh * DDIM + d) * SDIM + s] = o;  // V transposed
        }
      } else {
#pragma unroll
        for (int i = 0; i < 4; ++i)
          fout[(size_t)(rbase + i) * N + col] = acc[m][n][i] + bv;
      }
    }
  }
}

// ---------------- flash attention v3.1: paired tiles, glds 2-phase, swapped
// MFMA, bare v_exp_f32 softmax.
// qb,kb: [BH][S][D] bf16 ; vb: [BH][D][S] bf16 ; ao: [B*S][E] bf16
__global__ __launch_bounds__(256) void attn_mfma3(
    const short* __restrict__ qb, const short* __restrict__ kb,
    const short* __restrict__ vb, short* __restrict__ ao) {
  __shared__ short kvbuf[2][8192];   // [buf][ K 64x64 | V 64x64 ] bf16, swizzled
  __shared__ short pstrip[4][1024];  // per-wave P[16 qrow][64 key] bf16, swizzled

  const int tid = threadIdx.x;
  const int l = tid & 63, w = tid >> 6;
  const int lr = l & 15, g = l >> 4;
  const int swz = (lr & 7) << 4;

  const int lin = blockIdx.x;
  const int xcd = lin & 7;
  const int idx = lin >> 3;            // 0..95
  const int bh = xcd * 6 + (idx >> 4); // 0..47
  const int pair = idx & 15;
  const int tiles[2] = {NTILE - 1 - pair, pair};

  const int b = bh / HDIM, h = bh % HDIM;
  const size_t base = (size_t)bh * SDIM * DDIM;

  const int srow = w * 16 + (l >> 3);        // rows srow, srow+8 (it=0,1)
  const int sc = (l & 7) ^ (srow & 7);       // pre-swizzled source chunk
  const size_t koff0 = (size_t)srow * DDIM + sc * 8;
  const size_t koff1 = (size_t)(srow + 8) * DDIM + sc * 8;
  const size_t voff0 = (size_t)srow * SDIM + sc * 8;
  const size_t voff1 = (size_t)(srow + 8) * SDIM + sc * 8;

  const float SC = 0.125f * 1.4426950408889634f;  // scale * log2(e)
  char* sw = (char*)pstrip[w];

  for (int half = 0; half < 2; ++half) {
    const int tile = tiles[half];
    const int q0w = tile * 64 + w * 16;

    s16x8 qa[2];
#pragma unroll
    for (int s = 0; s < 2; ++s)
      qa[s] = *(const s16x8*)(qb + base + (size_t)(q0w + lr) * DDIM + s * 32 + g * 8);

    const f32x4 z4 = {0.f, 0.f, 0.f, 0.f};
    f32x4 acco[4];
#pragma unroll
    for (int nd = 0; nd < 4; ++nd) acco[nd] = z4;
    float mrun = -1e30f, lsum = 0.f;

    int cur = 0;
    {
      char* kd = (char*)kvbuf[cur] + w * 2048;
      const short* kp = kb + base;
      const short* vp = vb + base;
      gld16(kp + koff0, kd);
      gld16(kp + koff1, kd + 1024);
      gld16(vp + voff0, kd + 8192);
      gld16(vp + voff1, kd + 9216);
    }
    __syncthreads();

    for (int kt = 0; kt <= tile; ++kt) {
      if (kt < tile) {
        char* kd = (char*)kvbuf[cur ^ 1] + w * 2048;
        const short* kp = kb + base + (size_t)(kt + 1) * 64 * DDIM;
        const short* vp = vb + base + (size_t)(kt + 1) * 64;
        gld16(kp + koff0, kd);
        gld16(kp + koff1, kd + 1024);
        gld16(vp + voff0, kd + 8192);
        gld16(vp + voff1, kd + 9216);
      }

      const char* Kb = (const char*)kvbuf[cur];
      const char* Vb = Kb + 8192;

      f32x4 sacc[4];
#pragma unroll
      for (int nt = 0; nt < 4; ++nt) sacc[nt] = z4;
      __builtin_amdgcn_s_setprio(1);
#pragma unroll
      for (int s = 0; s < 2; ++s)
#pragma unroll
        for (int nt = 0; nt < 4; ++nt) {
          s16x8 kf = *(const s16x8*)(Kb + nt * 2048 + lr * 128 +
                                     ((s * 64 + g * 16) ^ swz));
          sacc[nt] = __builtin_amdgcn_mfma_f32_16x16x32_bf16(kf, qa[s],
                                                             sacc[nt], 0, 0, 0);
        }
      __builtin_amdgcn_s_setprio(0);

      if (kt == tile) {
        const int rloc = w * 16 + lr;
#pragma unroll
        for (int nt = 0; nt < 4; ++nt)
#pragma unroll
          for (int i = 0; i < 4; ++i)
            if (nt * 16 + g * 4 + i > rloc) sacc[nt][i] = -1e30f;
      }

      // row max via max3-friendly trees: per nt 3 ops, combine 3 ops, 2 shuffles
      float t0 = fmaxf(fmaxf(sacc[0][0], sacc[0][1]), fmaxf(sacc[0][2], sacc[0][3]));
      float t1 = fmaxf(fmaxf(sacc[1][0], sacc[1][1]), fmaxf(sacc[1][2], sacc[1][3]));
      float t2 = fmaxf(fmaxf(sacc[2][0], sacc[2][1]), fmaxf(sacc[2][2], sacc[2][3]));
      float t3 = fmaxf(fmaxf(sacc[3][0], sacc[3][1]), fmaxf(sacc[3][2], sacc[3][3]));
      float pmax = fmaxf(fmaxf(t0, t1), fmaxf(t2, t3));
      pmax = fmaxf(pmax, __shfl_xor(pmax, 16, 64));
      pmax = fmaxf(pmax, __shfl_xor(pmax, 32, 64));

      if (__any(pmax > mrun + 44.0f)) {
        float nm = fmaxf(mrun, pmax);
        float al = fexp2((mrun - nm) * SC);
        lsum *= al;
#pragma unroll
        for (int nd = 0; nd < 4; ++nd)
#pragma unroll
          for (int i = 0; i < 4; ++i) acco[nd][i] *= al;
        mrun = nm;
      }

      const float msc = mrun * SC;
#pragma unroll
      for (int nt = 0; nt < 4; ++nt) {
        float p0 = fexp2(__builtin_fmaf(sacc[nt][0], SC, -msc));
        float p1 = fexp2(__builtin_fmaf(sacc[nt][1], SC, -msc));
        float p2 = fexp2(__builtin_fmaf(sacc[nt][2], SC, -msc));
        float p3 = fexp2(__builtin_fmaf(sacc[nt][3], SC, -msc));
        lsum += (p0 + p1) + (p2 + p3);
        u32x2 pk = {cvtpk(p0, p1), cvtpk(p2, p3)};
        *(u32x2*)(sw + lr * 128 + (((nt * 32 + g * 8) ^ swz))) = pk;
      }

      __builtin_amdgcn_s_setprio(1);
#pragma unroll
      for (int s = 0; s < 2; ++s) {
        s16x8 pf = *(const s16x8*)(sw + lr * 128 + ((s * 64 + g * 16) ^ swz));
#pragma unroll
        for (int nd = 0; nd < 4; ++nd) {
          s16x8 vf = *(const s16x8*)(Vb + nd * 2048 + lr * 128 +
                                     ((s * 64 + g * 16) ^ swz));
          acco[nd] = __builtin_amdgcn_mfma_f32_16x16x32_bf16(vf, pf,
                                                             acco[nd], 0, 0, 0);
        }
      }
      __builtin_amdgcn_s_setprio(0);

      __syncthreads();
      cur ^= 1;
    }

    lsum += __shfl_xor(lsum, 16, 64);
    lsum += __shfl_xor(lsum, 32, 64);
    float inv = 1.0f / lsum;
    size_t orow = ((size_t)b * SDIM + q0w + lr) * EDIM + h * DDIM;
#pragma unroll
    for (int nd = 0; nd < 4; ++nd) {
      unsigned lo = cvtpk(acco[nd][0] * inv, acco[nd][1] * inv);
      unsigned hi = cvtpk(acco[nd][2] * inv, acco[nd][3] * inv);
      *(unsigned*)(ao + orow + nd * 16 + g * 4) = lo;
      *(unsigned*)(ao + orow + nd * 16 + g * 4 + 2) = hi;
    }
  }
}

extern "C" void kernel_launch(void* const* d_in, const int* in_sizes, int n_in,
                              void* d_out, int out_size, void* d_ws,
                              size_t ws_size, hipStream_t stream) {
  const float* x = (const float*)d_in[0];
  const float* w_qkv = (const float*)d_in[1];
  const float* b_qkv = (const float*)d_in[2];
  const float* w_proj = (const float*)d_in[3];
  const float* b_proj = (const float*)d_in[4];
  float* out = (float*)d_out;

  char* p = (char*)d_ws;
  short* xb = (short*)p;      p += (size_t)MROWS * EDIM * 2;
  short* wqkvt = (short*)p;   p += (size_t)NQKV * EDIM * 2;
  short* wprojt = (short*)p;  p += (size_t)EDIM * EDIM * 2;
  short* qbuf = (short*)p;    p += (size_t)NBH * SDIM * DDIM * 2;
  short* kbuf = (short*)p;    p += (size_t)NBH * SDIM * DDIM * 2;
  short* vbuf = (short*)p;    p += (size_t)NBH * SDIM * DDIM * 2;
  short* aob = (short*)p;     p += (size_t)MROWS * EDIM * 2;

  dim3 blk(256);
  convert_bf16<<<dim3(2048), blk, 0, stream>>>(x, xb, MROWS * EDIM / 4);
  transpose_bf16<<<dim3(NQKV / 32, EDIM / 32), blk, 0, stream>>>(w_qkv, wqkvt, EDIM, NQKV);
  transpose_bf16<<<dim3(EDIM / 32, EDIM / 32), blk, 0, stream>>>(w_proj, wprojt, EDIM, EDIM);
  gemm_bf16<<<dim3(NQKV / 128, MROWS / 128), blk, 0, stream>>>(
      xb, wqkvt, b_qkv, MROWS, NQKV, EDIM, 0, qbuf, kbuf, vbuf, nullptr);
  attn_mfma3<<<dim3(NPAIR * NBH), blk, 0, stream>>>(qbuf, kbuf, vbuf, aob);
  gemm_bf16<<<dim3(EDIM / 128, MROWS / 128), blk, 0, stream>>>(
      aob, wprojt, b_proj, MROWS, EDIM, EDIM, 1, nullptr, nullptr, nullptr, out);
}

// Round 7
// 140.030 us; speedup vs baseline: 2.7119x; 1.0792x over previous
//
#include <hip/hip_runtime.h>

#define SDIM 2048
#define EDIM 768
#define HDIM 12
#define DDIM 64
#define BDIM 4
#define MROWS (BDIM * SDIM)   // 8192
#define NQKV (3 * EDIM)       // 2304
#define NBH (BDIM * HDIM)     // 48
#define NTILE 32              // 2048 / 64 q-tiles
#define NPAIR 16

typedef __attribute__((ext_vector_type(8))) short s16x8;   // 8 bf16
typedef __attribute__((ext_vector_type(4))) float f32x4;
typedef __attribute__((ext_vector_type(2))) unsigned int u32x2;

__device__ __forceinline__ short f2b(float x) {
  union { float f; unsigned u; } v; v.f = x;
  unsigned r = v.u + 0x7fffu + ((v.u >> 16) & 1u);
  return (short)(r >> 16);
}

__device__ __forceinline__ unsigned cvtpk(float lo, float hi) {
  unsigned r;
  asm volatile("v_cvt_pk_bf16_f32 %0, %1, %2" : "=v"(r) : "v"(lo), "v"(hi));
  return r;
}

// bare v_exp_f32 (2^x)
__device__ __forceinline__ float fexp2(float x) {
  float r;
  asm("v_exp_f32 %0, %1" : "=v"(r) : "v"(x));
  return r;
}

__device__ __forceinline__ void gld16(const void* g, void* l) {
  __builtin_amdgcn_global_load_lds(
      (const __attribute__((address_space(1))) unsigned int*)g,
      (__attribute__((address_space(3))) unsigned int*)l, 16, 0, 0);
}

// ---------------- fused preprocessing: convert x + transpose both weights ----
// blocks [0, 1536): convert x (f32->bf16, 1024 float4 each)
// blocks [1536, 1536+1728): transpose w_qkv 32x32 tile
// blocks [1536+1728, +576): transpose w_proj 32x32 tile
__global__ __launch_bounds__(256) void preproc(
    const float* __restrict__ x, const float* __restrict__ wqkv,
    const float* __restrict__ wproj, short* __restrict__ xb,
    short* __restrict__ wqkvt, short* __restrict__ wprojt) {
  int bid = blockIdx.x;
  if (bid < 1536) {
    int i = bid * 256 + threadIdx.x;
    const int n4 = MROWS * EDIM / 4;
    for (; i < n4; i += 1536 * 256) {
      float4 v = ((const float4*)x)[i];
      short4 o;
      o.x = f2b(v.x); o.y = f2b(v.y); o.z = f2b(v.z); o.w = f2b(v.w);
      ((short4*)xb)[i] = o;
    }
    return;
  }
  const float* in; short* out; int K, N, t;
  if (bid < 1536 + 1728) { t = bid - 1536; in = wqkv; out = wqkvt; K = EDIM; N = NQKV; }
  else { t = bid - 1536 - 1728; in = wproj; out = wprojt; K = EDIM; N = EDIM; }
  const int ntx = N / 32;
  int n0 = (t % ntx) * 32, k0 = (t / ntx) * 32;
  __shared__ float tb[32][33];
  int tx = threadIdx.x & 31, ty = threadIdx.x >> 5;  // ty 0..7
#pragma unroll
  for (int i = 0; i < 4; ++i)
    tb[ty + 8 * i][tx] = in[(size_t)(k0 + ty + 8 * i) * N + n0 + tx];
  __syncthreads();
#pragma unroll
  for (int i = 0; i < 4; ++i)
    out[(size_t)(n0 + ty + 8 * i) * K + k0 + tx] = f2b(tb[tx][ty + 8 * i]);
}

// ---------------- bf16 MFMA GEMM v4 ----------------
// 128x128 tile, BK=32, 4 waves, triple-buffered glds w16, counted vmcnt(4),
// XCD-chunked block swizzle (grid%8==0), setprio around MFMA cluster.
// 1-D grid: ntx = N/128 tiles in x; bid -> (bm,bn) via XCD chunking.
__global__ __launch_bounds__(256) void gemm_bf16(
    const short* __restrict__ A, const short* __restrict__ Bt,
    const float* __restrict__ bias, int M, int N, int K, int mode,
    short* __restrict__ qout, short* __restrict__ kout,
    short* __restrict__ vout, float* __restrict__ fout) {
  __shared__ char lds[3][16384];  // [buf][ A 128x32 | B 128x32 ] bf16
  const int tid = threadIdx.x;
  const int l = tid & 63, w = tid >> 6;
  const int lr = l & 15, g = l >> 4;

  // XCD-chunked swizzle: gridDim.x % 8 == 0 guaranteed by launch
  const int chunk = gridDim.x >> 3;
  const int sid = (blockIdx.x & 7) * chunk + (blockIdx.x >> 3);
  const int ntx = N >> 7;
  const int bm = (sid / ntx) * 128, bn = (sid % ntx) * 128;
  const int wm = w >> 1, wn = w & 1;

  const int srow = w * 32 + (l >> 2);                    // + 0 / +16
  const int sc8 = (((l & 3) ^ ((l >> 3) & 3)) << 3);     // pre-swizzled k-elem
  const short* Ap0 = A + (size_t)(bm + srow) * K + sc8;
  const short* Bp0 = Bt + (size_t)(bn + srow) * K + sc8;

  f32x4 acc[4][4];
  const f32x4 z4 = {0.f, 0.f, 0.f, 0.f};
#pragma unroll
  for (int m = 0; m < 4; ++m)
#pragma unroll
    for (int n = 0; n < 4; ++n) acc[m][n] = z4;

#define STAGE(dst, t)                          \
  {                                            \
    char* Ad = (dst) + w * 2048;               \
    const short* Ap = Ap0 + (t) * 32;          \
    const short* Bp = Bp0 + (t) * 32;          \
    gld16(Ap, Ad);                             \
    gld16(Ap + 16 * K, Ad + 1024);             \
    gld16(Bp, Ad + 8192);                      \
    gld16(Bp + 16 * K, Ad + 9216);             \
  }

  const int nt = K >> 5;  // 24
  STAGE(lds[0], 0);
  STAGE(lds[1], 1);
  asm volatile("s_waitcnt vmcnt(4)" ::: "memory");
  __builtin_amdgcn_s_barrier();

  const int swz = ((lr >> 1) & 3) << 4;
  int bc = 0;  // compute buffer = t % 3
  for (int t = 0; t < nt; ++t) {
    if (t + 2 < nt) {
      int bs = bc + 2; if (bs >= 3) bs -= 3;
      STAGE(lds[bs], t + 2);
    }
    const char* Ab = lds[bc];
    const char* Bb = lds[bc] + 8192;
    s16x8 af[4], bfr[4];
#pragma unroll
    for (int m = 0; m < 4; ++m)
      af[m] = *(const s16x8*)(Ab + (wm * 64 + m * 16 + lr) * 64 + ((g << 4) ^ swz));
#pragma unroll
    for (int n = 0; n < 4; ++n)
      bfr[n] = *(const s16x8*)(Bb + (wn * 64 + n * 16 + lr) * 64 + ((g << 4) ^ swz));
    __builtin_amdgcn_s_setprio(1);
#pragma unroll
    for (int m = 0; m < 4; ++m)
#pragma unroll
      for (int n = 0; n < 4; ++n)
        acc[m][n] = __builtin_amdgcn_mfma_f32_16x16x32_bf16(af[m], bfr[n],
                                                            acc[m][n], 0, 0, 0);
    __builtin_amdgcn_s_setprio(0);
    if (t + 2 < nt) {
      asm volatile("s_waitcnt vmcnt(4)" ::: "memory");
      __builtin_amdgcn_s_barrier();
    } else if (t + 1 < nt) {
      asm volatile("s_waitcnt vmcnt(0)" ::: "memory");
      __builtin_amdgcn_s_barrier();
    }
    if (++bc == 3) bc = 0;
  }
#undef STAGE

#pragma unroll
  for (int m = 0; m < 4; ++m) {
    int rbase = bm + wm * 64 + m * 16 + g * 4;
#pragma unroll
    for (int n = 0; n < 4; ++n) {
      int col = bn + wn * 64 + n * 16 + lr;
      float bv = bias[col];
      if (mode == 0) {
        int which = (col >= 1536) ? 2 : (col >= 768 ? 1 : 0);
        int rem = col - which * 768;
        int h = rem >> 6, d = rem & 63;
#pragma unroll
        for (int i = 0; i < 4; ++i) {
          int r = rbase + i;
          int b = r >> 11, s = r & 2047;
          short o = f2b(acc[m][n][i] + bv);
          size_t bh = (size_t)b * HDIM + h;
          if (which == 0)      qout[(bh * SDIM + s) * DDIM + d] = o;
          else if (which == 1) kout[(bh * SDIM + s) * DDIM + d] = o;
          else                 vout[(bh * DDIM + d) * SDIM + s] = o;  // V transposed
        }
      } else {
#pragma unroll
        for (int i = 0; i < 4; ++i)
          fout[(size_t)(rbase + i) * N + col] = acc[m][n][i] + bv;
      }
    }
  }
}

// ---------------- flash attention v3.1 (unchanged from R6) ----------------
__global__ __launch_bounds__(256) void attn_mfma3(
    const short* __restrict__ qb, const short* __restrict__ kb,
    const short* __restrict__ vb, short* __restrict__ ao) {
  __shared__ short kvbuf[2][8192];
  __shared__ short pstrip[4][1024];

  const int tid = threadIdx.x;
  const int l = tid & 63, w = tid >> 6;
  const int lr = l & 15, g = l >> 4;
  const int swz = (lr & 7) << 4;

  const int lin = blockIdx.x;
  const int xcd = lin & 7;
  const int idx = lin >> 3;            // 0..95
  const int bh = xcd * 6 + (idx >> 4); // 0..47
  const int pair = idx & 15;
  const int tiles[2] = {NTILE - 1 - pair, pair};

  const int b = bh / HDIM, h = bh % HDIM;
  const size_t base = (size_t)bh * SDIM * DDIM;

  const int srow = w * 16 + (l >> 3);
  const int sc = (l & 7) ^ (srow & 7);
  const size_t koff0 = (size_t)srow * DDIM + sc * 8;
  const size_t koff1 = (size_t)(srow + 8) * DDIM + sc * 8;
  const size_t voff0 = (size_t)srow * SDIM + sc * 8;
  const size_t voff1 = (size_t)(srow + 8) * SDIM + sc * 8;

  const float SC = 0.125f * 1.4426950408889634f;
  char* sw = (char*)pstrip[w];

  for (int half = 0; half < 2; ++half) {
    const int tile = tiles[half];
    const int q0w = tile * 64 + w * 16;

    s16x8 qa[2];
#pragma unroll
    for (int s = 0; s < 2; ++s)
      qa[s] = *(const s16x8*)(qb + base + (size_t)(q0w + lr) * DDIM + s * 32 + g * 8);

    const f32x4 z4 = {0.f, 0.f, 0.f, 0.f};
    f32x4 acco[4];
#pragma unroll
    for (int nd = 0; nd < 4; ++nd) acco[nd] = z4;
    float mrun = -1e30f, lsum = 0.f;

    int cur = 0;
    {
      char* kd = (char*)kvbuf[cur] + w * 2048;
      const short* kp = kb + base;
      const short* vp = vb + base;
      gld16(kp + koff0, kd);
      gld16(kp + koff1, kd + 1024);
      gld16(vp + voff0, kd + 8192);
      gld16(vp + voff1, kd + 9216);
    }
    __syncthreads();

    for (int kt = 0; kt <= tile; ++kt) {
      if (kt < tile) {
        char* kd = (char*)kvbuf[cur ^ 1] + w * 2048;
        const short* kp = kb + base + (size_t)(kt + 1) * 64 * DDIM;
        const short* vp = vb + base + (size_t)(kt + 1) * 64;
        gld16(kp + koff0, kd);
        gld16(kp + koff1, kd + 1024);
        gld16(vp + voff0, kd + 8192);
        gld16(vp + voff1, kd + 9216);
      }

      const char* Kb = (const char*)kvbuf[cur];
      const char* Vb = Kb + 8192;

      f32x4 sacc[4];
#pragma unroll
      for (int nt = 0; nt < 4; ++nt) sacc[nt] = z4;
      __builtin_amdgcn_s_setprio(1);
#pragma unroll
      for (int s = 0; s < 2; ++s)
#pragma unroll
        for (int nt = 0; nt < 4; ++nt) {
          s16x8 kf = *(const s16x8*)(Kb + nt * 2048 + lr * 128 +
                                     ((s * 64 + g * 16) ^ swz));
          sacc[nt] = __builtin_amdgcn_mfma_f32_16x16x32_bf16(kf, qa[s],
                                                             sacc[nt], 0, 0, 0);
        }
      __builtin_amdgcn_s_setprio(0);

      if (kt == tile) {
        const int rloc = w * 16 + lr;
#pragma unroll
        for (int nt = 0; nt < 4; ++nt)
#pragma unroll
          for (int i = 0; i < 4; ++i)
            if (nt * 16 + g * 4 + i > rloc) sacc[nt][i] = -1e30f;
      }

      float t0 = fmaxf(fmaxf(sacc[0][0], sacc[0][1]), fmaxf(sacc[0][2], sacc[0][3]));
      float t1 = fmaxf(fmaxf(sacc[1][0], sacc[1][1]), fmaxf(sacc[1][2], sacc[1][3]));
      float t2 = fmaxf(fmaxf(sacc[2][0], sacc[2][1]), fmaxf(sacc[2][2], sacc[2][3]));
      float t3 = fmaxf(fmaxf(sacc[3][0], sacc[3][1]), fmaxf(sacc[3][2], sacc[3][3]));
      float pmax = fmaxf(fmaxf(t0, t1), fmaxf(t2, t3));
      pmax = fmaxf(pmax, __shfl_xor(pmax, 16, 64));
      pmax = fmaxf(pmax, __shfl_xor(pmax, 32, 64));

      if (__any(pmax > mrun + 44.0f)) {
        float nm = fmaxf(mrun, pmax);
        float al = fexp2((mrun - nm) * SC);
        lsum *= al;
#pragma unroll
        for (int nd = 0; nd < 4; ++nd)
#pragma unroll
          for (int i = 0; i < 4; ++i) acco[nd][i] *= al;
        mrun = nm;
      }

      const float msc = mrun * SC;
#pragma unroll
      for (int nt = 0; nt < 4; ++nt) {
        float p0 = fexp2(__builtin_fmaf(sacc[nt][0], SC, -msc));
        float p1 = fexp2(__builtin_fmaf(sacc[nt][1], SC, -msc));
        float p2 = fexp2(__builtin_fmaf(sacc[nt][2], SC, -msc));
        float p3 = fexp2(__builtin_fmaf(sacc[nt][3], SC, -msc));
        lsum += (p0 + p1) + (p2 + p3);
        u32x2 pk = {cvtpk(p0, p1), cvtpk(p2, p3)};
        *(u32x2*)(sw + lr * 128 + (((nt * 32 + g * 8) ^ swz))) = pk;
      }

      __builtin_amdgcn_s_setprio(1);
#pragma unroll
      for (int s = 0; s < 2; ++s) {
        s16x8 pf = *(const s16x8*)(sw + lr * 128 + ((s * 64 + g * 16) ^ swz));
#pragma unroll
        for (int nd = 0; nd < 4; ++nd) {
          s16x8 vf = *(const s16x8*)(Vb + nd * 2048 + lr * 128 +
                                     ((s * 64 + g * 16) ^ swz));
          acco[nd] = __builtin_amdgcn_mfma_f32_16x16x32_bf16(vf, pf,
                                                             acco[nd], 0, 0, 0);
        }
      }
      __builtin_amdgcn_s_setprio(0);

      __syncthreads();
      cur ^= 1;
    }

    lsum += __shfl_xor(lsum, 16, 64);
    lsum += __shfl_xor(lsum, 32, 64);
    float inv = 1.0f / lsum;
    size_t orow = ((size_t)b * SDIM + q0w + lr) * EDIM + h * DDIM;
#pragma unroll
    for (int nd = 0; nd < 4; ++nd) {
      unsigned lo = cvtpk(acco[nd][0] * inv, acco[nd][1] * inv);
      unsigned hi = cvtpk(acco[nd][2] * inv, acco[nd][3] * inv);
      *(unsigned*)(ao + orow + nd * 16 + g * 4) = lo;
      *(unsigned*)(ao + orow + nd * 16 + g * 4 + 2) = hi;
    }
  }
}

extern "C" void kernel_launch(void* const* d_in, const int* in_sizes, int n_in,
                              void* d_out, int out_size, void* d_ws,
                              size_t ws_size, hipStream_t stream) {
  const float* x = (const float*)d_in[0];
  const float* w_qkv = (const float*)d_in[1];
  const float* b_qkv = (const float*)d_in[2];
  const float* w_proj = (const float*)d_in[3];
  const float* b_proj = (const float*)d_in[4];
  float* out = (float*)d_out;

  char* p = (char*)d_ws;
  short* xb = (short*)p;      p += (size_t)MROWS * EDIM * 2;
  short* wqkvt = (short*)p;   p += (size_t)NQKV * EDIM * 2;
  short* wprojt = (short*)p;  p += (size_t)EDIM * EDIM * 2;
  short* qbuf = (short*)p;    p += (size_t)NBH * SDIM * DDIM * 2;
  short* kbuf = (short*)p;    p += (size_t)NBH * SDIM * DDIM * 2;
  short* vbuf = (short*)p;    p += (size_t)NBH * SDIM * DDIM * 2;
  short* aob = (short*)p;     p += (size_t)MROWS * EDIM * 2;

  dim3 blk(256);
  preproc<<<dim3(1536 + 1728 + 576), blk, 0, stream>>>(x, w_qkv, w_proj, xb,
                                                       wqkvt, wprojt);
  gemm_bf16<<<dim3((NQKV / 128) * (MROWS / 128)), blk, 0, stream>>>(
      xb, wqkvt, b_qkv, MROWS, NQKV, EDIM, 0, qbuf, kbuf, vbuf, nullptr);
  attn_mfma3<<<dim3(NPAIR * NBH), blk, 0, stream>>>(qbuf, kbuf, vbuf, aob);
  gemm_bf16<<<dim3((EDIM / 128) * (MROWS / 128)), blk, 0, stream>>>(
      aob, wprojt, b_proj, MROWS, EDIM, EDIM, 1, nullptr, nullptr, nullptr, out);
}